// Round 4
// baseline (332.773 us; speedup 1.0000x reference)
//
#include <hip/hip_runtime.h>
#include <hip/hip_bf16.h>
#include <math.h>

#define BB 2
#define SS 2048
#define EE 2048
#define NQ 16
#define NKV 4
#define HD 128
#define WINDOW 512

typedef __hip_bfloat16 bf16;
typedef short short8 __attribute__((ext_vector_type(8)));   // 8 bf16 (4 VGPRs)
typedef float f32x4 __attribute__((ext_vector_type(4)));

__device__ __forceinline__ float toF(bf16 v) { return __bfloat162float(v); }
__device__ __forceinline__ bf16 toB(float v) { return __float2bfloat16(v); }

// async global->LDS, 16B per lane. LDS dest = wave-uniform base + lane*16.
__device__ __forceinline__ void gld_lds16(const void* g, void* l) {
    __builtin_amdgcn_global_load_lds(
        (const __attribute__((address_space(1))) void*)g,
        (__attribute__((address_space(3))) void*)l, 16, 0, 0);
}

template <int V> __device__ __forceinline__ void waitvm() {
    if constexpr (V == 8)      asm volatile("s_waitcnt vmcnt(8)" ::: "memory");
    else if constexpr (V == 6) asm volatile("s_waitcnt vmcnt(6)" ::: "memory");
    else if constexpr (V == 4) asm volatile("s_waitcnt vmcnt(4)" ::: "memory");
    else if constexpr (V == 3) asm volatile("s_waitcnt vmcnt(3)" ::: "memory");
    else                       asm volatile("s_waitcnt vmcnt(0)" ::: "memory");
}

// ---------------------------------------------------------------------------
// fp32 -> bf16 elementwise (n % 4 == 0)
// ---------------------------------------------------------------------------
__global__ __launch_bounds__(256) void convert_bf16(const float* __restrict__ in,
                                                    bf16* __restrict__ out, int n) {
    int i = (blockIdx.x * 256 + threadIdx.x) * 4;
    if (i >= n) return;
    const float4 v = *(const float4*)(in + i);
    bf16 o[4] = {toB(v.x), toB(v.y), toB(v.z), toB(v.w)};
    *(uint2*)(out + i) = *(const uint2*)o;
}

// ---------------------------------------------------------------------------
// fp32 [K][N] -> bf16 [N][K] transpose. Generic (Wo).
// ---------------------------------------------------------------------------
__global__ __launch_bounds__(256) void convert_transpose(const float* __restrict__ in,
                                                         bf16* __restrict__ out,
                                                         int K, int N) {
    __shared__ float tile[32][33];
    const int t = threadIdx.x;
    const int tx = t & 31, ty = t >> 5;   // 32 x 8
    const int n0 = blockIdx.x * 32, k0 = blockIdx.y * 32;
#pragma unroll
    for (int r = 0; r < 4; r++)
        tile[ty + r * 8][tx] = in[(size_t)(k0 + ty + r * 8) * N + n0 + tx];
    __syncthreads();
#pragma unroll
    for (int r = 0; r < 4; r++)
        out[(size_t)(n0 + ty + r * 8) * K + k0 + tx] = toB(tile[tx][ty + r * 8]);
}

// ---------------------------------------------------------------------------
// Fused Wq/Wk/Wv transpose into packed [3072][2048] bf16.
// ---------------------------------------------------------------------------
__global__ __launch_bounds__(256) void convert_transpose_qkv(
    const float* __restrict__ Wq, const float* __restrict__ Wk,
    const float* __restrict__ Wv, bf16* __restrict__ out) {
    __shared__ float tile[32][33];
    const int t = threadIdx.x;
    const int tx = t & 31, ty = t >> 5;
    const int n0 = blockIdx.x * 32, k0 = blockIdx.y * 32;
    const float* src; int N, nl0;
    if (n0 < 2048)      { src = Wq; N = 2048; nl0 = n0; }
    else if (n0 < 2560) { src = Wk; N = 512;  nl0 = n0 - 2048; }
    else                { src = Wv; N = 512;  nl0 = n0 - 2560; }
#pragma unroll
    for (int r = 0; r < 4; r++)
        tile[ty + r * 8][tx] = src[(size_t)(k0 + ty + r * 8) * N + nl0 + tx];
    __syncthreads();
#pragma unroll
    for (int r = 0; r < 4; r++)
        out[(size_t)(n0 + ty + r * 8) * 2048 + k0 + tx] = toB(tile[tx][ty + r * 8]);
}

// ---------------------------------------------------------------------------
// MFMA GEMM v4: frag-pipelined, 4-deep LDS ring, one barrier per 32-k slice.
// Region r: { stage(slice r+3) ; ds_read frags(slice r+1) -> next (issued,
// NOT waited) ; MFMA(slice r) on cur (overlaps LDS service of the reads) ;
// lgkmcnt(0) ; vmcnt(SL) ; barrier }.
// RAW: vmcnt(SL) leaves only the newest stage outstanding -> slice r+2
//   landed before the barrier preceding its readers (cross-wave via barrier).
// WAR: stage(r+3) overwrites buf[(r-1)&3]; all waves' reads of slice r-1
//   completed (lgkmcnt) before the barrier at end of region r-2 -> safe.
// XOR swizzle (measured 0-conflict in round 2): 16B slot s of row r holds
// k-group s ^ ((r>>1)&3); reads use slot lq ^ ((row>>1)&3).
// 512 threads = 8 waves, 2M x 4N. MODE 0: fp32 out + bias. MODE 1: packed
// QKV split routed PER 16-col FRAGMENT (tiles straddle region boundaries),
// RoPE fused for Q/K, V stored transposed [b][hkv][d][s].
// ---------------------------------------------------------------------------
template <int MODE, int BM, int BN>
__global__ __launch_bounds__(512, 2) void mfma_gemm_v4(
    const bf16* __restrict__ A, const bf16* __restrict__ BT,
    const float* __restrict__ b0, const float* __restrict__ b1,
    const float* __restrict__ b2,
    float* __restrict__ Yf,
    bf16* __restrict__ Yq, bf16* __restrict__ Yk, bf16* __restrict__ Yv,
    int M, int N, int K) {
    constexpr int NI = BM / 32;            // A frags per wave (2M split)
    constexpr int NJ = BN / 64;            // B frags per wave (4N split)
    constexpr int LA = BM / 128;           // gld_lds per A slice per wave
    constexpr int LB = BN / 128;
    constexpr int SL = LA + LB;            // loads per slice-stage per wave

    __shared__ __align__(16) bf16 As[4][BM * 32];
    __shared__ __align__(16) bf16 Bs[4][BN * 32];

    const int t = threadIdx.x;
    const int lane = t & 63;
    const int w = t >> 6;                  // 0..7
    const int wm = w >> 2;                 // 0..1
    const int wn = w & 3;                  // 0..3
    const int m0 = blockIdx.y * BM, n0 = blockIdx.x * BN;
    const int lr = lane & 15;
    const int lq = lane >> 4;
    const int NT = K >> 5;                 // 32-k slices (even; 64 here)

    // stage slice s into ring buffer s&3 (pre-swizzled global source)
    auto stage = [&](int s) {
        bf16* Ad = &As[s & 3][0];
#pragma unroll
        for (int l = 0; l < LA; l++) {
            const int c = w * LA + l;
            const int row = c * 16 + (lane >> 2);
            const int g = (lane & 3) ^ ((row >> 1) & 3);
            gld_lds16(A + (size_t)(m0 + row) * K + s * 32 + g * 8, Ad + c * 512);
        }
        bf16* Bd = &Bs[s & 3][0];
#pragma unroll
        for (int l = 0; l < LB; l++) {
            const int c = w * LB + l;
            const int row = c * 16 + (lane >> 2);
            const int g = (lane & 3) ^ ((row >> 1) & 3);
            gld_lds16(BT + (size_t)(n0 + row) * K + s * 32 + g * 8, Bd + c * 512);
        }
    };

    // issue fragment reads for slice s (no wait)
    auto loadfr = [&](int s, short8 (&fA)[NI], short8 (&fB)[NJ]) {
        const bf16* Asl = &As[s & 3][0];
        const bf16* Bsl = &Bs[s & 3][0];
#pragma unroll
        for (int i = 0; i < NI; i++) {
            const int row = wm * (NI * 16) + i * 16 + lr;
            const int sl = lq ^ ((row >> 1) & 3);
            fA[i] = *(const short8*)(Asl + row * 32 + sl * 8);
        }
#pragma unroll
        for (int j = 0; j < NJ; j++) {
            const int row = wn * (NJ * 16) + j * 16 + lr;
            const int sl = lq ^ ((row >> 1) & 3);
            fB[j] = *(const short8*)(Bsl + row * 32 + sl * 8);
        }
    };

    f32x4 acc[NI][NJ];
#pragma unroll
    for (int i = 0; i < NI; i++)
#pragma unroll
        for (int j = 0; j < NJ; j++) acc[i][j] = (f32x4)0.f;

    auto region = [&](int r, short8 (&fAc)[NI], short8 (&fBc)[NJ],
                             short8 (&fAn)[NI], short8 (&fBn)[NJ]) {
        if (r + 3 < NT) stage(r + 3);
        if (r + 1 < NT) loadfr(r + 1, fAn, fBn);
        __builtin_amdgcn_sched_barrier(0);   // pin: stage+read issues precede MFMA
        __builtin_amdgcn_s_setprio(1);
#pragma unroll
        for (int i = 0; i < NI; i++)
#pragma unroll
            for (int j = 0; j < NJ; j++)
                acc[i][j] = __builtin_amdgcn_mfma_f32_16x16x32_bf16(fAc[i], fBc[j],
                                                                    acc[i][j], 0, 0, 0);
        __builtin_amdgcn_s_setprio(0);
        asm volatile("s_waitcnt lgkmcnt(0)" ::: "memory");
        if (r + 3 < NT) waitvm<SL>(); else waitvm<0>();
        __builtin_amdgcn_sched_barrier(0);   // nothing crosses the waits
        __builtin_amdgcn_s_barrier();
    };

    // prologue: 3 slices in the ring; slices 0,1 guaranteed landed
    stage(0); stage(1); stage(2);
    waitvm<SL>();
    __builtin_amdgcn_s_barrier();
    short8 fA0[NI], fB0[NJ], fA1[NI], fB1[NJ];
    loadfr(0, fA0, fB0);
    asm volatile("s_waitcnt lgkmcnt(0)" ::: "memory");
    __builtin_amdgcn_sched_barrier(0);

    for (int r = 0; r < NT; r += 2) {
        region(r,     fA0, fB0, fA1, fB1);
        region(r + 1, fA1, fB1, fA0, fB0);
    }

    if (MODE == 0) {
#pragma unroll
        for (int j = 0; j < NJ; j++) {
            const int col = n0 + wn * (NJ * 16) + j * 16 + lr;
            const float bj = b0[col];
#pragma unroll
            for (int i = 0; i < NI; i++) {
                const int row = m0 + wm * (NI * 16) + i * 16 + lq * 4;
#pragma unroll
                for (int r = 0; r < 4; r++)
                    Yf[(size_t)(row + r) * N + col] = acc[i][j][r] + bj;
            }
        }
    } else {
        // per-16-col-fragment routing (tiles straddle the 2048/2560 splits)
#pragma unroll
        for (int j = 0; j < NJ; j++) {
            const int gcol = n0 + wn * (NJ * 16) + j * 16 + lr;
            if (gcol < 2560) {
                bf16* outp; const float* bias; int ldc, col;
                if (gcol < 2048) { outp = Yq; bias = b0; ldc = 2048; col = gcol; }
                else             { outp = Yk; bias = b1; ldc = 512;  col = gcol - 2048; }
                const float bj = bias[col];
                const int d2 = (col & 127) >> 1;
                const bool odd = col & 1;
                const float freq = __expf(-0.14384103622589045f * (float)d2); // ln(1e4)*2/128
#pragma unroll
                for (int i = 0; i < NI; i++) {
                    const int row = m0 + wm * (NI * 16) + i * 16 + lq * 4;
#pragma unroll
                    for (int r = 0; r < 4; r++) {
                        const float v = acc[i][j][r] + bj;
                        const float p = __shfl_xor(v, 1, 64);
                        const float ang = (float)((row + r) & (SS - 1)) * freq;
                        float sn, cs;
                        __sincosf(ang, &sn, &cs);
                        const float o = odd ? (p * sn + v * cs) : (v * cs - p * sn);
                        outp[(size_t)(row + r) * ldc + col] = toB(o);
                    }
                }
            } else {
                // V: store transposed [b][hkv][d][s]; 4 acc rows = 4 consecutive s.
                const int col = gcol - 2560;       // 0..511
                const float bj = b2[col];
                const int hkv = col >> 7, d = col & 127;
#pragma unroll
                for (int i = 0; i < NI; i++) {
                    const int row = m0 + wm * (NI * 16) + i * 16 + lq * 4;
                    const int bb = row >> 11, sr = row & (SS - 1);
                    union { bf16 b[4]; uint2 u; } o4;
#pragma unroll
                    for (int r = 0; r < 4; r++) o4.b[r] = toB(acc[i][j][r] + bj);
                    *(uint2*)(Yv + (((size_t)bb * NKV + hkv) * HD + d) * SS + sr) = o4.u;
                }
            }
        }
    }
}

// ---------------------------------------------------------------------------
// MFMA flash attention, windowed causal, GQA (unchanged).
// ---------------------------------------------------------------------------
__global__ __launch_bounds__(256) void attn_mfma(const bf16* __restrict__ Q,
                                                 const bf16* __restrict__ K,
                                                 const bf16* __restrict__ VT,
                                                 bf16* __restrict__ Oout) {
    __shared__ bf16 Ks[64 * 128];      // [key][d], slot-swizzled
    __shared__ bf16 Vs[128 * 64];      // [d][key] (V^T), slot-swizzled
    __shared__ bf16 Ps[4 * 16 * 72];   // per-wave P tile, pad 72

    const int t = threadIdx.x;
    const int lane = t & 63;
    const int w = t >> 6;
    const int q0 = blockIdx.x * 64;
    const int h = blockIdx.y;
    const int b = blockIdx.z;
    const int hkv = h >> 2;
    const int lr = lane & 15;
    const int lq = lane >> 4;
    const float scale = 0.08838834764831845f;  // 1/sqrt(128)

    short8 aq[4];
    {
        const int q = q0 + w * 16 + lr;
        const bf16* qp = Q + (((size_t)b * SS + q) * NQ + h) * HD + lq * 8;
#pragma unroll
        for (int ks = 0; ks < 4; ks++) aq[ks] = *(const short8*)(qp + ks * 32);
    }

    const int krow = w * 16 + (lane >> 4);
    const int vrow = w * 32 + (lane >> 3);
    const bf16* Kbase = K + ((size_t)b * SS * NKV + hkv) * HD;
    const bf16* Vbase = VT + (((size_t)b * NKV + hkv) * HD) * SS;

    f32x4 Oa[8];
#pragma unroll
    for (int nb = 0; nb < 8; nb++) Oa[nb] = (f32x4)0.f;
    float mprev[4] = {-3.0e38f, -3.0e38f, -3.0e38f, -3.0e38f};
    float lsum[4] = {0.f, 0.f, 0.f, 0.f};

    bf16* Pw = Ps + w * 16 * 72;
    const int jstart = (q0 >= WINDOW) ? (q0 - WINDOW) : 0;

    for (int c0 = jstart; c0 <= q0; c0 += 64) {
        __syncthreads();
#pragma unroll
        for (int s = 0; s < 4; s++) {
            const int r_ = krow + s * 4;
            const int g_ = (lane & 15) ^ (r_ & 7);
            gld_lds16(Kbase + (size_t)(c0 + r_) * (NKV * HD) + g_ * 8,
                      Ks + (w * 16 + s * 4) * 128);
        }
#pragma unroll
        for (int s = 0; s < 4; s++) {
            const int d_ = vrow + s * 8;
            const int g_ = (lane & 7) ^ (d_ & 7);
            gld_lds16(Vbase + (size_t)d_ * SS + c0 + g_ * 8,
                      Vs + (w * 32 + s * 8) * 64);
        }
        __syncthreads();

        f32x4 sa[4];
#pragma unroll
        for (int nb = 0; nb < 4; nb++) sa[nb] = (f32x4)0.f;
#pragma unroll
        for (int ks = 0; ks < 4; ks++) {
#pragma unroll
            for (int nb = 0; nb < 4; nb++) {
                const int slot = (ks * 4 + lq) ^ (lr & 7);
                short8 bk = *(const short8*)(Ks + (nb * 16 + lr) * 128 + slot * 8);
                sa[nb] = __builtin_amdgcn_mfma_f32_16x16x32_bf16(aq[ks], bk, sa[nb], 0, 0, 0);
            }
        }

        const int rowb = q0 + w * 16 + lq * 4;
        const bool noMask = (c0 + 63 <= q0 + w * 16) &&
                            (q0 + w * 16 + 15 - c0 <= WINDOW);
        float pr[4][4], alpha[4];
#pragma unroll
        for (int r = 0; r < 4; r++) {
            const int row = rowb + r;
            float sv[4];
            float mx = -3.0e38f;
            if (noMask) {
#pragma unroll
                for (int nb = 0; nb < 4; nb++) {
                    const float s = sa[nb][r] * scale;
                    sv[nb] = s;
                    mx = fmaxf(mx, s);
                }
            } else {
#pragma unroll
                for (int nb = 0; nb < 4; nb++) {
                    const int col = c0 + nb * 16 + lr;
                    const bool valid = (col <= row) && (row - col <= WINDOW);
                    const float s = valid ? sa[nb][r] * scale : -3.0e38f;
                    sv[nb] = s;
                    mx = fmaxf(mx, s);
                }
            }
#pragma unroll
            for (int off = 1; off < 16; off <<= 1) mx = fmaxf(mx, __shfl_xor(mx, off, 64));
            const float mn = fmaxf(fmaxf(mprev[r], mx), -1.0e30f);
            alpha[r] = __expf(mprev[r] - mn);
            mprev[r] = mn;
            float rs = 0.f;
#pragma unroll
            for (int nb = 0; nb < 4; nb++) {
                const float p = __expf(sv[nb] - mn);
                pr[r][nb] = p;
                rs += p;
            }
#pragma unroll
            for (int off = 1; off < 16; off <<= 1) rs += __shfl_xor(rs, off, 64);
            lsum[r] = lsum[r] * alpha[r] + rs;
        }

#pragma unroll
        for (int r = 0; r < 4; r++)
#pragma unroll
            for (int nb = 0; nb < 4; nb++)
                Pw[(lq * 4 + r) * 72 + nb * 16 + lr] = toB(pr[r][nb]);

#pragma unroll
        for (int nb = 0; nb < 8; nb++)
#pragma unroll
            for (int r = 0; r < 4; r++) Oa[nb][r] *= alpha[r];
#pragma unroll
        for (int ks = 0; ks < 2; ks++) {
            short8 pa = *(const short8*)(Pw + lr * 72 + ks * 32 + lq * 8);
#pragma unroll
            for (int nb = 0; nb < 8; nb++) {
                const int slot = (ks * 4 + lq) ^ (lr & 7);
                short8 bv = *(const short8*)(Vs + (nb * 16 + lr) * 64 + slot * 8);
                Oa[nb] = __builtin_amdgcn_mfma_f32_16x16x32_bf16(pa, bv, Oa[nb], 0, 0, 0);
            }
        }
    }

    float linv[4];
#pragma unroll
    for (int r = 0; r < 4; r++) linv[r] = 1.f / lsum[r];
    const int rowb = q0 + w * 16 + lq * 4;
#pragma unroll
    for (int nb = 0; nb < 8; nb++)
#pragma unroll
        for (int r = 0; r < 4; r++)
            Oout[(((size_t)b * SS + rowb + r) * NQ + h) * HD + nb * 16 + lr] =
                toB(Oa[nb][r] * linv[r]);
}

// ---------------------------------------------------------------------------
extern "C" void kernel_launch(void* const* d_in, const int* in_sizes, int n_in,
                              void* d_out, int out_size, void* d_ws, size_t ws_size,
                              hipStream_t stream) {
    const float* x  = (const float*)d_in[0];
    const float* Wq = (const float*)d_in[1];
    const float* bq = (const float*)d_in[2];
    const float* Wk = (const float*)d_in[3];
    const float* bk = (const float*)d_in[4];
    const float* Wv = (const float*)d_in[5];
    const float* bv = (const float*)d_in[6];
    const float* Wo = (const float*)d_in[7];
    const float* bo = (const float*)d_in[8];
    float* out = (float*)d_out;

    const int M   = BB * SS;       // 4096
    const int DQ  = NQ * HD;       // 2048
    const int DKV = NKV * HD;      // 512
    const int NPK = DQ + 2 * DKV;  // 3072

    bf16* xb     = (bf16*)d_ws;                       // 4096*2048
    bf16* WqkvT  = xb + (size_t)M * EE;               // 3072*2048
    bf16* WoT    = WqkvT + (size_t)NPK * EE;          // 2048*2048
    bf16* Qb     = WoT + (size_t)EE * DQ;             // 4096*2048 (attn out in-place)
    bf16* Kb     = Qb + (size_t)M * DQ;               // 4096*512
    bf16* Vb     = Kb + (size_t)M * DKV;              // 4096*512  (V^T layout)

    convert_bf16<<<(M * EE / 4 + 255) / 256, 256, 0, stream>>>(x, xb, M * EE);
    convert_transpose_qkv<<<dim3(NPK / 32, EE / 32), 256, 0, stream>>>(Wq, Wk, Wv, WqkvT);
    convert_transpose<<<dim3(DQ / 32, DQ / 32), 256, 0, stream>>>(Wo, WoT, DQ, EE);

    // fused QKV projection + bias + RoPE; 128x384 tile -> 8x32 = 256 blocks
    mfma_gemm_v4<1, 128, 384><<<dim3(NPK / 384, M / 128), 512, 0, stream>>>(
        xb, WqkvT, bq, bk, bv, nullptr, Qb, Kb, Vb, M, NPK, EE);

    attn_mfma<<<dim3(SS / 64, NQ, BB), 256, 0, stream>>>(Qb, Kb, Vb, Qb);

    // out projection; 128x256 tile -> 8x32 = 256 blocks (full CU fill)
    mfma_gemm_v4<0, 128, 256><<<dim3(EE / 256, M / 128), 512, 0, stream>>>(
        Qb, WoT, bo, nullptr, nullptr, out, nullptr, nullptr, nullptr, M, EE, DQ);
}

// Round 6
// 312.641 us; speedup vs baseline: 1.0644x; 1.0644x over previous
//
#include <hip/hip_runtime.h>
#include <hip/hip_bf16.h>
#include <math.h>

#define BB 2
#define SS 2048
#define EE 2048
#define NQ 16
#define NKV 4
#define HD 128
#define WINDOW 512

typedef __hip_bfloat16 bf16;
typedef short short8 __attribute__((ext_vector_type(8)));   // 8 bf16 (4 VGPRs)
typedef float f32x4 __attribute__((ext_vector_type(4)));

__device__ __forceinline__ float toF(bf16 v) { return __bfloat162float(v); }
__device__ __forceinline__ bf16 toB(float v) { return __float2bfloat16(v); }

// async global->LDS, 16B per lane. LDS dest = wave-uniform base + lane*16.
__device__ __forceinline__ void gld_lds16(const void* g, void* l) {
    __builtin_amdgcn_global_load_lds(
        (const __attribute__((address_space(1))) void*)g,
        (__attribute__((address_space(3))) void*)l, 16, 0, 0);
}

template <int V> __device__ __forceinline__ void waitvm() {
    if constexpr (V == 8)      asm volatile("s_waitcnt vmcnt(8)" ::: "memory");
    else if constexpr (V == 6) asm volatile("s_waitcnt vmcnt(6)" ::: "memory");
    else if constexpr (V == 5) asm volatile("s_waitcnt vmcnt(5)" ::: "memory");
    else if constexpr (V == 4) asm volatile("s_waitcnt vmcnt(4)" ::: "memory");
    else if constexpr (V == 3) asm volatile("s_waitcnt vmcnt(3)" ::: "memory");
    else                       asm volatile("s_waitcnt vmcnt(0)" ::: "memory");
}
__device__ __forceinline__ void waitlgkm0() {
    asm volatile("s_waitcnt lgkmcnt(0)" ::: "memory");
}

// ---------------------------------------------------------------------------
// fp32 -> bf16 elementwise (n % 4 == 0)
// ---------------------------------------------------------------------------
__global__ __launch_bounds__(256) void convert_bf16(const float* __restrict__ in,
                                                    bf16* __restrict__ out, int n) {
    int i = (blockIdx.x * 256 + threadIdx.x) * 4;
    if (i >= n) return;
    const float4 v = *(const float4*)(in + i);
    bf16 o[4] = {toB(v.x), toB(v.y), toB(v.z), toB(v.w)};
    *(uint2*)(out + i) = *(const uint2*)o;
}

// ---------------------------------------------------------------------------
// fp32 [K][N] -> bf16 [N][K] transpose. Generic (Wo).
// ---------------------------------------------------------------------------
__global__ __launch_bounds__(256) void convert_transpose(const float* __restrict__ in,
                                                         bf16* __restrict__ out,
                                                         int K, int N) {
    __shared__ float tile[32][33];
    const int t = threadIdx.x;
    const int tx = t & 31, ty = t >> 5;   // 32 x 8
    const int n0 = blockIdx.x * 32, k0 = blockIdx.y * 32;
#pragma unroll
    for (int r = 0; r < 4; r++)
        tile[ty + r * 8][tx] = in[(size_t)(k0 + ty + r * 8) * N + n0 + tx];
    __syncthreads();
#pragma unroll
    for (int r = 0; r < 4; r++)
        out[(size_t)(n0 + ty + r * 8) * K + k0 + tx] = toB(tile[tx][ty + r * 8]);
}

// ---------------------------------------------------------------------------
// Fused Wq/Wk/Wv transpose into packed [3072][2048] bf16.
// ---------------------------------------------------------------------------
__global__ __launch_bounds__(256) void convert_transpose_qkv(
    const float* __restrict__ Wq, const float* __restrict__ Wk,
    const float* __restrict__ Wv, bf16* __restrict__ out) {
    __shared__ float tile[32][33];
    const int t = threadIdx.x;
    const int tx = t & 31, ty = t >> 5;
    const int n0 = blockIdx.x * 32, k0 = blockIdx.y * 32;
    const float* src; int N, nl0;
    if (n0 < 2048)      { src = Wq; N = 2048; nl0 = n0; }
    else if (n0 < 2560) { src = Wk; N = 512;  nl0 = n0 - 2048; }
    else                { src = Wv; N = 512;  nl0 = n0 - 2560; }
#pragma unroll
    for (int r = 0; r < 4; r++)
        tile[ty + r * 8][tx] = src[(size_t)(k0 + ty + r * 8) * N + nl0 + tx];
    __syncthreads();
#pragma unroll
    for (int r = 0; r < 4; r++)
        out[(size_t)(n0 + ty + r * 8) * 2048 + k0 + tx] = toB(tile[tx][ty + r * 8]);
}

// ---------------------------------------------------------------------------
// MFMA GEMM v6 = ring-3 pipeline (v5) + XCD-slab tile swizzle (T1).
//
// XCD swizzle: lin = y*gx + x; hardware round-robins lin%8 across XCDs.
// XCD c owns m-tile rows [c*gy/8, (c+1)*gy/8) traversed n-major: the slab's
// A panels stay L2-resident; each B panel is fetched once per XCD and
// reused gy/8 times back-to-back. Requires gy % 8 == 0 (both grids: gy=32).
//
// Ring-3 region t (one BK=64 K-tile, ring slot t%3):
//   stage(t+2); ds_read(t,kk1)->f1; MFMA(t,kk0) [overlaps f1 LDS service];
//   lgkmcnt(0); vmcnt(SL) [stage(t+1) complete - a FULL region of slack];
//   s_barrier; ds_read(t+1,kk0)->f0; MFMA(t,kk1).
// RAW: every wave's vmcnt(SL) precedes the barrier => tile t+1 landed before
//   any post-barrier read. WAR: stage(t+3) (post next barrier) overwrites
//   slot t%3; all reads of tile t drained by this region's lgkm0+barrier.
// XOR swizzle (r2-proven 0-conflict): 16B slot s of row r holds k-group
// s^(r&7); readers use slot ((kk*4+lq)^(row&7)).
// 512 thr = 8 waves (2M x 4N). MODE 0: fp32+bias. MODE 1: per-16-col-frag
// QKV routing, RoPE fused for Q/K, V stored transposed [b][hkv][d][s].
// ---------------------------------------------------------------------------
template <int MODE, int BM, int BN>
__global__ __launch_bounds__(512, 2) void mfma_gemm_v6(
    const bf16* __restrict__ A, const bf16* __restrict__ BT,
    const float* __restrict__ b0, const float* __restrict__ b1,
    const float* __restrict__ b2,
    float* __restrict__ Yf,
    bf16* __restrict__ Yq, bf16* __restrict__ Yk, bf16* __restrict__ Yv,
    int M, int N, int K) {
    constexpr int NI = BM / 2 / 16;        // A frags per wave per kk
    constexpr int NJ = BN / 4 / 16;        // B frags per wave per kk
    constexpr int LA = BM / 64;            // gld_lds per thread for A stage
    constexpr int LB = BN / 64;
    constexpr int SL = LA + LB;

    __shared__ __align__(16) bf16 As[3][BM * 64];
    __shared__ __align__(16) bf16 Bs[3][BN * 64];

    const int tid = threadIdx.x;
    const int lane = tid & 63;
    const int w = tid >> 6;                // 0..7
    const int wm = w >> 2;                 // 0..1
    const int wn = w & 3;                  // 0..3

    // ---- XCD-slab tile mapping (bijective; gy % 8 == 0) ----
    const int gx = gridDim.x, gy = gridDim.y;
    const int lin = blockIdx.y * gx + blockIdx.x;
    const int xcd = lin & 7;
    const int idx = lin >> 3;
    const int rpx = gy >> 3;               // m-tiles per XCD slab (4)
    const int tn = idx / rpx;
    const int tm = xcd * rpx + (idx % rpx);
    const int m0 = tm * BM, n0 = tn * BN;

    const int lr = lane & 15;
    const int lq = lane >> 4;
    const int NT = K >> 6;                 // 32 for K=2048

    const int srow = tid >> 3;             // 0..63: row within 64-row chunk
    const int sslot = tid & 7;             // 16B slot within 128B row

    // stage K-tile s into ring slot s%3; dest linear (HW adds lane*16B);
    // source pre-swizzled: k-group = sslot ^ (row&7).
    auto stage = [&](int s) {
        bf16* Ad = &As[s % 3][0];
#pragma unroll
        for (int l = 0; l < LA; l++) {
            const int row = l * 64 + srow;
            const int g = sslot ^ (row & 7);
            gld_lds16(A + (size_t)(m0 + row) * K + s * 64 + g * 8,
                      Ad + l * 4096 + w * 512);
        }
        bf16* Bd = &Bs[s % 3][0];
#pragma unroll
        for (int l = 0; l < LB; l++) {
            const int row = l * 64 + srow;
            const int g = sslot ^ (row & 7);
            gld_lds16(BT + (size_t)(n0 + row) * K + s * 64 + g * 8,
                      Bd + l * 4096 + w * 512);
        }
    };

    // fragment reads for (tile s, k-half kk)
    auto readf = [&](int s, int kk, short8 (&fA)[NI], short8 (&fB)[NJ]) {
        const bf16* Asl = &As[s % 3][0];
        const bf16* Bsl = &Bs[s % 3][0];
#pragma unroll
        for (int i = 0; i < NI; i++) {
            const int row = wm * (NI * 16) + i * 16 + lr;
            const int sl = ((kk << 2) | lq) ^ (row & 7);
            fA[i] = *(const short8*)(Asl + row * 64 + sl * 8);
        }
#pragma unroll
        for (int j = 0; j < NJ; j++) {
            const int row = wn * (NJ * 16) + j * 16 + lr;
            const int sl = ((kk << 2) | lq) ^ (row & 7);
            fB[j] = *(const short8*)(Bsl + row * 64 + sl * 8);
        }
    };

    f32x4 acc[NI][NJ];
#pragma unroll
    for (int i = 0; i < NI; i++)
#pragma unroll
        for (int j = 0; j < NJ; j++) acc[i][j] = (f32x4)0.f;

    auto cluster = [&](short8 (&fA)[NI], short8 (&fB)[NJ]) {
        __builtin_amdgcn_s_setprio(1);
#pragma unroll
        for (int i = 0; i < NI; i++)
#pragma unroll
            for (int j = 0; j < NJ; j++)
                acc[i][j] = __builtin_amdgcn_mfma_f32_16x16x32_bf16(fA[i], fB[j],
                                                                    acc[i][j], 0, 0, 0);
        __builtin_amdgcn_s_setprio(0);
    };

    // prologue: tiles 0,1 staged; wait tile 0; first frag read.
    stage(0); stage(1);
    waitvm<SL>();
    __builtin_amdgcn_s_barrier();
    __builtin_amdgcn_sched_barrier(0);
    short8 fA0[NI], fB0[NJ], fA1[NI], fB1[NJ];
    readf(0, 0, fA0, fB0);

    for (int t = 0; t < NT; ++t) {
        if (t + 2 < NT) stage(t + 2);
        readf(t, 1, fA1, fB1);
        cluster(fA0, fB0);                 // kk0; overlaps f1 LDS service
        waitlgkm0();                       // own reads done (WAR proof)
        if (t + 2 < NT) waitvm<SL>(); else waitvm<0>();
        __builtin_amdgcn_s_barrier();
        __builtin_amdgcn_sched_barrier(0);
        if (t + 1 < NT) readf(t + 1, 0, fA0, fB0);
        cluster(fA1, fB1);                 // kk1; overlaps f0 LDS service
    }

    if (MODE == 0) {
#pragma unroll
        for (int j = 0; j < NJ; j++) {
            const int col = n0 + wn * (NJ * 16) + j * 16 + lr;
            const float bj = b0[col];
#pragma unroll
            for (int i = 0; i < NI; i++) {
                const int row = m0 + wm * (NI * 16) + i * 16 + lq * 4;
#pragma unroll
                for (int r = 0; r < 4; r++)
                    Yf[(size_t)(row + r) * N + col] = acc[i][j][r] + bj;
            }
        }
    } else {
        // per-16-col-fragment routing (boundaries 2048/2560 are 16-aligned)
#pragma unroll
        for (int j = 0; j < NJ; j++) {
            const int gcol = n0 + wn * (NJ * 16) + j * 16 + lr;
            if (gcol < 2560) {
                bf16* outp; const float* bias; int ldc, col;
                if (gcol < 2048) { outp = Yq; bias = b0; ldc = 2048; col = gcol; }
                else             { outp = Yk; bias = b1; ldc = 512;  col = gcol - 2048; }
                const float bj = bias[col];
                const int d2 = (col & 127) >> 1;
                const bool odd = col & 1;
                const float freq = __expf(-0.14384103622589045f * (float)d2); // ln(1e4)*2/128
#pragma unroll
                for (int i = 0; i < NI; i++) {
                    const int row = m0 + wm * (NI * 16) + i * 16 + lq * 4;
#pragma unroll
                    for (int r = 0; r < 4; r++) {
                        const float v = acc[i][j][r] + bj;
                        const float p = __shfl_xor(v, 1, 64);
                        const float ang = (float)((row + r) & (SS - 1)) * freq;
                        float sn, cs;
                        __sincosf(ang, &sn, &cs);
                        const float o = odd ? (p * sn + v * cs) : (v * cs - p * sn);
                        outp[(size_t)(row + r) * ldc + col] = toB(o);
                    }
                }
            } else {
                // V: store transposed [b][hkv][d][s]; 4 acc rows = 4 consecutive s.
                const int col = gcol - 2560;       // 0..511
                const float bj = b2[col];
                const int hkv = col >> 7, d = col & 127;
#pragma unroll
                for (int i = 0; i < NI; i++) {
                    const int row = m0 + wm * (NI * 16) + i * 16 + lq * 4;
                    const int bb = row >> 11, sr = row & (SS - 1);
                    union { bf16 b[4]; uint2 u; } o4;
#pragma unroll
                    for (int r = 0; r < 4; r++) o4.b[r] = toB(acc[i][j][r] + bj);
                    *(uint2*)(Yv + (((size_t)bb * NKV + hkv) * HD + d) * SS + sr) = o4.u;
                }
            }
        }
    }
}

// ---------------------------------------------------------------------------
// MFMA flash attention, windowed causal, GQA (unchanged).
// ---------------------------------------------------------------------------
__global__ __launch_bounds__(256) void attn_mfma(const bf16* __restrict__ Q,
                                                 const bf16* __restrict__ K,
                                                 const bf16* __restrict__ VT,
                                                 bf16* __restrict__ Oout) {
    __shared__ bf16 Ks[64 * 128];      // [key][d], slot-swizzled
    __shared__ bf16 Vs[128 * 64];      // [d][key] (V^T), slot-swizzled
    __shared__ bf16 Ps[4 * 16 * 72];   // per-wave P tile, pad 72

    const int t = threadIdx.x;
    const int lane = t & 63;
    const int w = t >> 6;
    const int q0 = blockIdx.x * 64;
    const int h = blockIdx.y;
    const int b = blockIdx.z;
    const int hkv = h >> 2;
    const int lr = lane & 15;
    const int lq = lane >> 4;
    const float scale = 0.08838834764831845f;  // 1/sqrt(128)

    short8 aq[4];
    {
        const int q = q0 + w * 16 + lr;
        const bf16* qp = Q + (((size_t)b * SS + q) * NQ + h) * HD + lq * 8;
#pragma unroll
        for (int ks = 0; ks < 4; ks++) aq[ks] = *(const short8*)(qp + ks * 32);
    }

    const int krow = w * 16 + (lane >> 4);
    const int vrow = w * 32 + (lane >> 3);
    const bf16* Kbase = K + ((size_t)b * SS * NKV + hkv) * HD;
    const bf16* Vbase = VT + (((size_t)b * NKV + hkv) * HD) * SS;

    f32x4 Oa[8];
#pragma unroll
    for (int nb = 0; nb < 8; nb++) Oa[nb] = (f32x4)0.f;
    float mprev[4] = {-3.0e38f, -3.0e38f, -3.0e38f, -3.0e38f};
    float lsum[4] = {0.f, 0.f, 0.f, 0.f};

    bf16* Pw = Ps + w * 16 * 72;
    const int jstart = (q0 >= WINDOW) ? (q0 - WINDOW) : 0;

    for (int c0 = jstart; c0 <= q0; c0 += 64) {
        __syncthreads();
#pragma unroll
        for (int s = 0; s < 4; s++) {
            const int r_ = krow + s * 4;
            const int g_ = (lane & 15) ^ (r_ & 7);
            gld_lds16(Kbase + (size_t)(c0 + r_) * (NKV * HD) + g_ * 8,
                      Ks + (w * 16 + s * 4) * 128);
        }
#pragma unroll
        for (int s = 0; s < 4; s++) {
            const int d_ = vrow + s * 8;
            const int g_ = (lane & 7) ^ (d_ & 7);
            gld_lds16(Vbase + (size_t)d_ * SS + c0 + g_ * 8,
                      Vs + (w * 32 + s * 8) * 64);
        }
        __syncthreads();

        f32x4 sa[4];
#pragma unroll
        for (int nb = 0; nb < 4; nb++) sa[nb] = (f32x4)0.f;
#pragma unroll
        for (int ks = 0; ks < 4; ks++) {
#pragma unroll
            for (int nb = 0; nb < 4; nb++) {
                const int slot = (ks * 4 + lq) ^ (lr & 7);
                short8 bk = *(const short8*)(Ks + (nb * 16 + lr) * 128 + slot * 8);
                sa[nb] = __builtin_amdgcn_mfma_f32_16x16x32_bf16(aq[ks], bk, sa[nb], 0, 0, 0);
            }
        }

        const int rowb = q0 + w * 16 + lq * 4;
        const bool noMask = (c0 + 63 <= q0 + w * 16) &&
                            (q0 + w * 16 + 15 - c0 <= WINDOW);
        float pr[4][4], alpha[4];
#pragma unroll
        for (int r = 0; r < 4; r++) {
            const int row = rowb + r;
            float sv[4];
            float mx = -3.0e38f;
            if (noMask) {
#pragma unroll
                for (int nb = 0; nb < 4; nb++) {
                    const float s = sa[nb][r] * scale;
                    sv[nb] = s;
                    mx = fmaxf(mx, s);
                }
            } else {
#pragma unroll
                for (int nb = 0; nb < 4; nb++) {
                    const int col = c0 + nb * 16 + lr;
                    const bool valid = (col <= row) && (row - col <= WINDOW);
                    const float s = valid ? sa[nb][r] * scale : -3.0e38f;
                    sv[nb] = s;
                    mx = fmaxf(mx, s);
                }
            }
#pragma unroll
            for (int off = 1; off < 16; off <<= 1) mx = fmaxf(mx, __shfl_xor(mx, off, 64));
            const float mn = fmaxf(fmaxf(mprev[r], mx), -1.0e30f);
            alpha[r] = __expf(mprev[r] - mn);
            mprev[r] = mn;
            float rs = 0.f;
#pragma unroll
            for (int nb = 0; nb < 4; nb++) {
                const float p = __expf(sv[nb] - mn);
                pr[r][nb] = p;
                rs += p;
            }
#pragma unroll
            for (int off = 1; off < 16; off <<= 1) rs += __shfl_xor(rs, off, 64);
            lsum[r] = lsum[r] * alpha[r] + rs;
        }

#pragma unroll
        for (int r = 0; r < 4; r++)
#pragma unroll
            for (int nb = 0; nb < 4; nb++)
                Pw[(lq * 4 + r) * 72 + nb * 16 + lr] = toB(pr[r][nb]);

#pragma unroll
        for (int nb = 0; nb < 8; nb++)
#pragma unroll
            for (int r = 0; r < 4; r++) Oa[nb][r] *= alpha[r];
#pragma unroll
        for (int ks = 0; ks < 2; ks++) {
            short8 pa = *(const short8*)(Pw + lr * 72 + ks * 32 + lq * 8);
#pragma unroll
            for (int nb = 0; nb < 8; nb++) {
                const int slot = (ks * 4 + lq) ^ (lr & 7);
                short8 bv = *(const short8*)(Vs + (nb * 16 + lr) * 64 + slot * 8);
                Oa[nb] = __builtin_amdgcn_mfma_f32_16x16x32_bf16(pa, bv, Oa[nb], 0, 0, 0);
            }
        }
    }

    float linv[4];
#pragma unroll
    for (int r = 0; r < 4; r++) linv[r] = 1.f / lsum[r];
    const int rowb = q0 + w * 16 + lq * 4;
#pragma unroll
    for (int nb = 0; nb < 8; nb++)
#pragma unroll
        for (int r = 0; r < 4; r++)
            Oout[(((size_t)b * SS + rowb + r) * NQ + h) * HD + nb * 16 + lr] =
                toB(Oa[nb][r] * linv[r]);
}

// ---------------------------------------------------------------------------
extern "C" void kernel_launch(void* const* d_in, const int* in_sizes, int n_in,
                              void* d_out, int out_size, void* d_ws, size_t ws_size,
                              hipStream_t stream) {
    const float* x  = (const float*)d_in[0];
    const float* Wq = (const float*)d_in[1];
    const float* bq = (const float*)d_in[2];
    const float* Wk = (const float*)d_in[3];
    const float* bk = (const float*)d_in[4];
    const float* Wv = (const float*)d_in[5];
    const float* bv = (const float*)d_in[6];
    const float* Wo = (const float*)d_in[7];
    const float* bo = (const float*)d_in[8];
    float* out = (float*)d_out;

    const int M   = BB * SS;       // 4096
    const int DQ  = NQ * HD;       // 2048
    const int DKV = NKV * HD;      // 512
    const int NPK = DQ + 2 * DKV;  // 3072

    bf16* xb     = (bf16*)d_ws;                       // 4096*2048
    bf16* WqkvT  = xb + (size_t)M * EE;               // 3072*2048
    bf16* WoT    = WqkvT + (size_t)NPK * EE;          // 2048*2048
    bf16* Qb     = WoT + (size_t)EE * DQ;             // 4096*2048 (attn out in-place)
    bf16* Kb     = Qb + (size_t)M * DQ;               // 4096*512
    bf16* Vb     = Kb + (size_t)M * DKV;              // 4096*512  (V^T layout)

    convert_bf16<<<(M * EE / 4 + 255) / 256, 256, 0, stream>>>(x, xb, M * EE);
    convert_transpose_qkv<<<dim3(NPK / 32, EE / 32), 256, 0, stream>>>(Wq, Wk, Wv, WqkvT);
    convert_transpose<<<dim3(DQ / 32, DQ / 32), 256, 0, stream>>>(Wo, WoT, DQ, EE);

    // QKV projection + bias + RoPE; 128x192 tile, ring-3, XCD-slab swizzle
    mfma_gemm_v6<1, 128, 192><<<dim3(NPK / 192, M / 128), 512, 0, stream>>>(
        xb, WqkvT, bq, bk, bv, nullptr, Qb, Kb, Vb, M, NPK, EE);

    attn_mfma<<<dim3(SS / 64, NQ, BB), 256, 0, stream>>>(Qb, Kb, Vb, Qb);

    // out projection; 128x256 tile, ring-3, XCD-slab swizzle
    mfma_gemm_v6<0, 128, 256><<<dim3(EE / 256, M / 128), 512, 0, stream>>>(
        Qb, WoT, bo, nullptr, nullptr, out, nullptr, nullptr, nullptr, M, EE, DQ);
}

// Round 7
// 309.581 us; speedup vs baseline: 1.0749x; 1.0099x over previous
//
#include <hip/hip_runtime.h>
#include <hip/hip_bf16.h>
#include <math.h>

#define BB 2
#define SS 2048
#define EE 2048
#define NQ 16
#define NKV 4
#define HD 128
#define WINDOW 512

typedef __hip_bfloat16 bf16;
typedef short short8 __attribute__((ext_vector_type(8)));   // 8 bf16 (4 VGPRs)
typedef float f32x4 __attribute__((ext_vector_type(4)));
typedef float f32x16 __attribute__((ext_vector_type(16)));

__device__ __forceinline__ float toF(bf16 v) { return __bfloat162float(v); }
__device__ __forceinline__ bf16 toB(float v) { return __float2bfloat16(v); }

// async global->LDS, 16B per lane. LDS dest = wave-uniform base + lane*16.
__device__ __forceinline__ void gld_lds16(const void* g, void* l) {
    __builtin_amdgcn_global_load_lds(
        (const __attribute__((address_space(1))) void*)g,
        (__attribute__((address_space(3))) void*)l, 16, 0, 0);
}

template <int V> __device__ __forceinline__ void waitvm() {
    if constexpr (V == 8)      asm volatile("s_waitcnt vmcnt(8)" ::: "memory");
    else if constexpr (V == 6) asm volatile("s_waitcnt vmcnt(6)" ::: "memory");
    else if constexpr (V == 4) asm volatile("s_waitcnt vmcnt(4)" ::: "memory");
    else if constexpr (V == 3) asm volatile("s_waitcnt vmcnt(3)" ::: "memory");
    else                       asm volatile("s_waitcnt vmcnt(0)" ::: "memory");
}
__device__ __forceinline__ void waitlgkm0() {
    asm volatile("s_waitcnt lgkmcnt(0)" ::: "memory");
}

// ---------------------------------------------------------------------------
// fp32 -> bf16 elementwise (n % 4 == 0)
// ---------------------------------------------------------------------------
__global__ __launch_bounds__(256) void convert_bf16(const float* __restrict__ in,
                                                    bf16* __restrict__ out, int n) {
    int i = (blockIdx.x * 256 + threadIdx.x) * 4;
    if (i >= n) return;
    const float4 v = *(const float4*)(in + i);
    bf16 o[4] = {toB(v.x), toB(v.y), toB(v.z), toB(v.w)};
    *(uint2*)(out + i) = *(const uint2*)o;
}

// ---------------------------------------------------------------------------
// fp32 [K][N] -> bf16 [N][K] transpose. Generic (Wo).
// ---------------------------------------------------------------------------
__global__ __launch_bounds__(256) void convert_transpose(const float* __restrict__ in,
                                                         bf16* __restrict__ out,
                                                         int K, int N) {
    __shared__ float tile[32][33];
    const int t = threadIdx.x;
    const int tx = t & 31, ty = t >> 5;   // 32 x 8
    const int n0 = blockIdx.x * 32, k0 = blockIdx.y * 32;
#pragma unroll
    for (int r = 0; r < 4; r++)
        tile[ty + r * 8][tx] = in[(size_t)(k0 + ty + r * 8) * N + n0 + tx];
    __syncthreads();
#pragma unroll
    for (int r = 0; r < 4; r++)
        out[(size_t)(n0 + ty + r * 8) * K + k0 + tx] = toB(tile[tx][ty + r * 8]);
}

// ---------------------------------------------------------------------------
// Fused Wq/Wk/Wv transpose into packed [3072][2048] bf16.
// ---------------------------------------------------------------------------
__global__ __launch_bounds__(256) void convert_transpose_qkv(
    const float* __restrict__ Wq, const float* __restrict__ Wk,
    const float* __restrict__ Wv, bf16* __restrict__ out) {
    __shared__ float tile[32][33];
    const int t = threadIdx.x;
    const int tx = t & 31, ty = t >> 5;
    const int n0 = blockIdx.x * 32, k0 = blockIdx.y * 32;
    const float* src; int N, nl0;
    if (n0 < 2048)      { src = Wq; N = 2048; nl0 = n0; }
    else if (n0 < 2560) { src = Wk; N = 512;  nl0 = n0 - 2048; }
    else                { src = Wv; N = 512;  nl0 = n0 - 2560; }
#pragma unroll
    for (int r = 0; r < 4; r++)
        tile[ty + r * 8][tx] = src[(size_t)(k0 + ty + r * 8) * N + nl0 + tx];
    __syncthreads();
#pragma unroll
    for (int r = 0; r < 4; r++)
        out[(size_t)(n0 + ty + r * 8) * 2048 + k0 + tx] = toB(tile[tx][ty + r * 8]);
}

// ---------------------------------------------------------------------------
// MFMA GEMM v7: 32x32x16 MFMA + ring-3 (BK=32) + 3 blocks/CU co-residency.
// 128x128 tile, 256 thr = 4 waves (2M x 2N), wave out 64x64 = 2x2 of 32x32.
// LDS 48 KB (3-slot ring) -> 3 blocks/CU; __launch_bounds__(256,3) caps VGPR.
// Ring-3 region t (one BK=32 tile, slot t%3):
//   stage(t+2) [4 gld_lds]; ds_read(t,ks1)->f1; MFMA(t,ks0) on f0;
//   lgkmcnt(0); vmcnt(4) [stage(t+1), issued LAST region, landed];
//   s_barrier; ds_read(t+1,ks0)->f0; MFMA(t,ks1) on f1.
// RAW/WAR proofs identical to r6 (passed). XOR swizzle: 16B slot s of row r
// holds k-group s ^ ((r>>1)&3) -> 8 consecutive rows hit 8 distinct
// bank-quads on frag reads (measured-0-conflict pattern).
// 32x32x16 layouts: A/B frag: lane l holds row/col l&31, k = (l>>5)*8+e.
// C/D: col = l&31, row = (reg&3) + 8*(reg>>2) + 4*(l>>5)  [m74/m101].
// XCD slab mapping (r6): lin%8 -> XCD owns gy/8 contiguous m-rows, n-major.
// MODE 0: fp32 out + bias. MODE 1: per-32-col-tile QKV routing, RoPE fused
// for Q/K, V stored transposed [b][hkv][d][s].
// ---------------------------------------------------------------------------
template <int MODE>
__global__ __launch_bounds__(256, 3) void mfma_gemm_v7(
    const bf16* __restrict__ A, const bf16* __restrict__ BT,
    const float* __restrict__ b0, const float* __restrict__ b1,
    const float* __restrict__ b2,
    float* __restrict__ Yf,
    bf16* __restrict__ Yq, bf16* __restrict__ Yk, bf16* __restrict__ Yv,
    int M, int N, int K) {
    constexpr int SL = 4;                  // gld_lds per thread per stage (2A+2B)

    __shared__ __align__(16) bf16 As[3][128 * 32];   // 24 KB
    __shared__ __align__(16) bf16 Bs[3][128 * 32];   // 24 KB

    const int tid = threadIdx.x;
    const int lane = tid & 63;
    const int w = tid >> 6;                // 0..3
    const int wm = w >> 1;                 // 0..1
    const int wn = w & 1;                  // 0..1

    // ---- XCD-slab tile mapping (bijective; gy % 8 == 0) ----
    const int gx = gridDim.x, gy = gridDim.y;
    const int lin = blockIdx.y * gx + blockIdx.x;
    const int xcd = lin & 7;
    const int idx = lin >> 3;
    const int rpx = gy >> 3;
    const int tn = idx / rpx;
    const int tm = xcd * rpx + (idx % rpx);
    const int m0 = tm * 128, n0 = tn * 128;

    const int l31 = lane & 31;
    const int l5  = lane >> 5;             // 0/1 (k-chunk select)
    const int NT = K >> 5;                 // BK=32

    // stage tile s into ring slot s%3. Per thread: 2 A + 2 B gld_lds.
    // chunk c = w*2+l covers rows c*16..c*16+15 (1 KB); lane -> row c*16+(lane>>2),
    // dest slot lane&3; source logical k-group = (lane&3) ^ ((row>>1)&3).
    auto stage = [&](int s) {
        bf16* Ad = &As[s % 3][0];
#pragma unroll
        for (int l = 0; l < 2; l++) {
            const int c = w * 2 + l;
            const int row = c * 16 + (lane >> 2);
            const int g = (lane & 3) ^ ((row >> 1) & 3);
            gld_lds16(A + (size_t)(m0 + row) * K + s * 32 + g * 8, Ad + c * 512);
        }
        bf16* Bd = &Bs[s % 3][0];
#pragma unroll
        for (int l = 0; l < 2; l++) {
            const int c = w * 2 + l;
            const int row = c * 16 + (lane >> 2);
            const int g = (lane & 3) ^ ((row >> 1) & 3);
            gld_lds16(BT + (size_t)(n0 + row) * K + s * 32 + g * 8, Bd + c * 512);
        }
    };

    // fragment reads for (tile s, k-step ks in {0,1}): A rows wm*64+i2*32+l31,
    // logical slot ks*2+l5, stored slot ^ ((row>>1)&3).
    auto readf = [&](int s, int ks, short8 (&fA)[2], short8 (&fB)[2]) {
        const bf16* Asl = &As[s % 3][0];
        const bf16* Bsl = &Bs[s % 3][0];
#pragma unroll
        for (int i = 0; i < 2; i++) {
            const int row = wm * 64 + i * 32 + l31;
            const int sl = (ks * 2 + l5) ^ ((row >> 1) & 3);
            fA[i] = *(const short8*)(Asl + row * 32 + sl * 8);
        }
#pragma unroll
        for (int j = 0; j < 2; j++) {
            const int row = wn * 64 + j * 32 + l31;
            const int sl = (ks * 2 + l5) ^ ((row >> 1) & 3);
            fB[j] = *(const short8*)(Bsl + row * 32 + sl * 8);
        }
    };

    f32x16 acc[2][2];
#pragma unroll
    for (int i = 0; i < 2; i++)
#pragma unroll
        for (int j = 0; j < 2; j++) acc[i][j] = (f32x16)0.f;

    auto cluster = [&](short8 (&fA)[2], short8 (&fB)[2]) {
        __builtin_amdgcn_s_setprio(1);
#pragma unroll
        for (int i = 0; i < 2; i++)
#pragma unroll
            for (int j = 0; j < 2; j++)
                acc[i][j] = __builtin_amdgcn_mfma_f32_32x32x16_bf16(fA[i], fB[j],
                                                                    acc[i][j], 0, 0, 0);
        __builtin_amdgcn_s_setprio(0);
    };

    // prologue
    stage(0); stage(1);
    waitvm<SL>();
    __builtin_amdgcn_s_barrier();
    __builtin_amdgcn_sched_barrier(0);
    short8 fA0[2], fB0[2], fA1[2], fB1[2];
    readf(0, 0, fA0, fB0);

    for (int t = 0; t < NT; ++t) {
        if (t + 2 < NT) stage(t + 2);
        readf(t, 1, fA1, fB1);
        cluster(fA0, fB0);                 // ks0
        waitlgkm0();
        if (t + 2 < NT) waitvm<SL>(); else waitvm<0>();
        __builtin_amdgcn_s_barrier();
        __builtin_amdgcn_sched_barrier(0);
        if (t + 1 < NT) readf(t + 1, 0, fA0, fB0);
        cluster(fA1, fB1);                 // ks1
    }

    // ---- epilogue: C/D map col=l31, row=(reg&3)+8*(reg>>2)+4*l5 ----
    if (MODE == 0) {
#pragma unroll
        for (int j = 0; j < 2; j++) {
            const int col = n0 + wn * 64 + j * 32 + l31;
            const float bj = b0[col];
#pragma unroll
            for (int i = 0; i < 2; i++) {
                const int rb = m0 + wm * 64 + i * 32 + 4 * l5;
#pragma unroll
                for (int reg = 0; reg < 16; reg++) {
                    const int row = rb + (reg & 3) + 8 * (reg >> 2);
                    Yf[(size_t)row * N + col] = acc[i][j][reg] + bj;
                }
            }
        }
    } else {
        // per-32-col-tile routing (boundaries 2048/2560 are 32-aligned)
#pragma unroll
        for (int j = 0; j < 2; j++) {
            const int gcol = n0 + wn * 64 + j * 32 + l31;
            if (gcol < 2560) {
                bf16* outp; const float* bias; int ldc, col;
                if (gcol < 2048) { outp = Yq; bias = b0; ldc = 2048; col = gcol; }
                else             { outp = Yk; bias = b1; ldc = 512;  col = gcol - 2048; }
                const float bj = bias[col];
                const int d2 = (col & 127) >> 1;
                const bool odd = col & 1;
                const float freq = __expf(-0.14384103622589045f * (float)d2); // ln(1e4)*2/128
#pragma unroll
                for (int i = 0; i < 2; i++) {
                    const int rb = m0 + wm * 64 + i * 32 + 4 * l5;
#pragma unroll
                    for (int reg = 0; reg < 16; reg++) {
                        const int row = rb + (reg & 3) + 8 * (reg >> 2);
                        const float v = acc[i][j][reg] + bj;
                        const float p = __shfl_xor(v, 1, 64);   // col pair (same row)
                        const float ang = (float)(row & (SS - 1)) * freq;
                        float sn, cs;
                        __sincosf(ang, &sn, &cs);
                        const float o = odd ? (p * sn + v * cs) : (v * cs - p * sn);
                        outp[(size_t)row * ldc + col] = toB(o);
                    }
                }
            } else {
                // V transposed [b][hkv][d][s]; regs rg*4+r are 4 consecutive rows.
                const int col = gcol - 2560;       // 0..511
                const float bj = b2[col];
                const int hkv = col >> 7, d = col & 127;
#pragma unroll
                for (int i = 0; i < 2; i++) {
                    const int rb = m0 + wm * 64 + i * 32 + 4 * l5;
#pragma unroll
                    for (int rg = 0; rg < 4; rg++) {
                        const int row = rb + 8 * rg;        // rows row..row+3
                        const int bb = row >> 11, sr = row & (SS - 1);
                        union { bf16 b[4]; uint2 u; } o4;
#pragma unroll
                        for (int r = 0; r < 4; r++) o4.b[r] = toB(acc[i][j][rg * 4 + r] + bj);
                        *(uint2*)(Yv + (((size_t)bb * NKV + hkv) * HD + d) * SS + sr) = o4.u;
                    }
                }
            }
        }
    }
}

// ---------------------------------------------------------------------------
// MFMA flash attention, windowed causal, GQA. v7: K/V double-buffered —
// stage chunk c+1 (8 gld_lds) issued BEFORE compute of chunk c; the trailing
// __syncthreads (drains vmcnt) lands after ~1500 cyc of compute -> HBM
// latency hidden. WAR: buf^1 was last read in chunk c-1, whose reads retired
// before its closing barrier. LDS 73 KB -> 2 blocks/CU.
// ---------------------------------------------------------------------------
__global__ __launch_bounds__(256) void attn_mfma(const bf16* __restrict__ Q,
                                                 const bf16* __restrict__ K,
                                                 const bf16* __restrict__ VT,
                                                 bf16* __restrict__ Oout) {
    __shared__ bf16 Ks[2][64 * 128];   // [key][d], slot-swizzled
    __shared__ bf16 Vs[2][128 * 64];   // [d][key] (V^T), slot-swizzled
    __shared__ bf16 Ps[4 * 16 * 72];   // per-wave P tile, pad 72

    const int t = threadIdx.x;
    const int lane = t & 63;
    const int w = t >> 6;
    const int q0 = blockIdx.x * 64;
    const int h = blockIdx.y;
    const int b = blockIdx.z;
    const int hkv = h >> 2;
    const int lr = lane & 15;
    const int lq = lane >> 4;
    const float scale = 0.08838834764831845f;  // 1/sqrt(128)

    short8 aq[4];
    {
        const int q = q0 + w * 16 + lr;
        const bf16* qp = Q + (((size_t)b * SS + q) * NQ + h) * HD + lq * 8;
#pragma unroll
        for (int ks = 0; ks < 4; ks++) aq[ks] = *(const short8*)(qp + ks * 32);
    }

    const int krow = w * 16 + (lane >> 4);
    const int vrow = w * 32 + (lane >> 3);
    const bf16* Kbase = K + ((size_t)b * SS * NKV + hkv) * HD;
    const bf16* Vbase = VT + (((size_t)b * NKV + hkv) * HD) * SS;

    // stage K/V chunk starting at key c0s into buffer bufi
    auto stageKV = [&](int c0s, int bufi) {
        bf16* Kd = &Ks[bufi][0];
        bf16* Vd = &Vs[bufi][0];
#pragma unroll
        for (int s = 0; s < 4; s++) {
            const int r_ = krow + s * 4;
            const int g_ = (lane & 15) ^ (r_ & 7);
            gld_lds16(Kbase + (size_t)(c0s + r_) * (NKV * HD) + g_ * 8,
                      Kd + (w * 16 + s * 4) * 128);
        }
#pragma unroll
        for (int s = 0; s < 4; s++) {
            const int d_ = vrow + s * 8;
            const int g_ = (lane & 7) ^ (d_ & 7);
            gld_lds16(Vbase + (size_t)d_ * SS + c0s + g_ * 8,
                      Vd + (w * 32 + s * 8) * 64);
        }
    };

    f32x4 Oa[8];
#pragma unroll
    for (int nb = 0; nb < 8; nb++) Oa[nb] = (f32x4)0.f;
    float mprev[4] = {-3.0e38f, -3.0e38f, -3.0e38f, -3.0e38f};
    float lsum[4] = {0.f, 0.f, 0.f, 0.f};

    bf16* Pw = Ps + w * 16 * 72;
    const int jstart = (q0 >= WINDOW) ? (q0 - WINDOW) : 0;

    // prologue: first chunk into buf 0
    stageKV(jstart, 0);
    asm volatile("s_waitcnt vmcnt(0)" ::: "memory");
    __syncthreads();

    int cb = 0;
    for (int c0 = jstart; c0 <= q0; c0 += 64) {
        if (c0 + 64 <= q0) stageKV(c0 + 64, cb ^ 1);   // hidden under compute
        const bf16* Ksb = &Ks[cb][0];
        const bf16* Vsb = &Vs[cb][0];

        f32x4 sa[4];
#pragma unroll
        for (int nb = 0; nb < 4; nb++) sa[nb] = (f32x4)0.f;
#pragma unroll
        for (int ks = 0; ks < 4; ks++) {
#pragma unroll
            for (int nb = 0; nb < 4; nb++) {
                const int slot = (ks * 4 + lq) ^ (lr & 7);
                short8 bk = *(const short8*)(Ksb + (nb * 16 + lr) * 128 + slot * 8);
                sa[nb] = __builtin_amdgcn_mfma_f32_16x16x32_bf16(aq[ks], bk, sa[nb], 0, 0, 0);
            }
        }

        const int rowb = q0 + w * 16 + lq * 4;
        const bool noMask = (c0 + 63 <= q0 + w * 16) &&
                            (q0 + w * 16 + 15 - c0 <= WINDOW);
        float pr[4][4], alpha[4];
#pragma unroll
        for (int r = 0; r < 4; r++) {
            const int row = rowb + r;
            float sv[4];
            float mx = -3.0e38f;
            if (noMask) {
#pragma unroll
                for (int nb = 0; nb < 4; nb++) {
                    const float s = sa[nb][r] * scale;
                    sv[nb] = s;
                    mx = fmaxf(mx, s);
                }
            } else {
#pragma unroll
                for (int nb = 0; nb < 4; nb++) {
                    const int col = c0 + nb * 16 + lr;
                    const bool valid = (col <= row) && (row - col <= WINDOW);
                    const float s = valid ? sa[nb][r] * scale : -3.0e38f;
                    sv[nb] = s;
                    mx = fmaxf(mx, s);
                }
            }
#pragma unroll
            for (int off = 1; off < 16; off <<= 1) mx = fmaxf(mx, __shfl_xor(mx, off, 64));
            const float mn = fmaxf(fmaxf(mprev[r], mx), -1.0e30f);
            alpha[r] = __expf(mprev[r] - mn);
            mprev[r] = mn;
            float rs = 0.f;
#pragma unroll
            for (int nb = 0; nb < 4; nb++) {
                const float p = __expf(sv[nb] - mn);
                pr[r][nb] = p;
                rs += p;
            }
#pragma unroll
            for (int off = 1; off < 16; off <<= 1) rs += __shfl_xor(rs, off, 64);
            lsum[r] = lsum[r] * alpha[r] + rs;
        }

#pragma unroll
        for (int r = 0; r < 4; r++)
#pragma unroll
            for (int nb = 0; nb < 4; nb++)
                Pw[(lq * 4 + r) * 72 + nb * 16 + lr] = toB(pr[r][nb]);

#pragma unroll
        for (int nb = 0; nb < 8; nb++)
#pragma unroll
            for (int r = 0; r < 4; r++) Oa[nb][r] *= alpha[r];
#pragma unroll
        for (int ks = 0; ks < 2; ks++) {
            short8 pa = *(const short8*)(Pw + lr * 72 + ks * 32 + lq * 8);
#pragma unroll
            for (int nb = 0; nb < 8; nb++) {
                const int slot = (ks * 4 + lq) ^ (lr & 7);
                short8 bv = *(const short8*)(Vsb + (nb * 16 + lr) * 64 + slot * 8);
                Oa[nb] = __builtin_amdgcn_mfma_f32_16x16x32_bf16(pa, bv, Oa[nb], 0, 0, 0);
            }
        }

        __syncthreads();   // drains vmcnt (stage already hidden) + WAR epoch
        cb ^= 1;
    }

    float linv[4];
#pragma unroll
    for (int r = 0; r < 4; r++) linv[r] = 1.f / lsum[r];
    const int rowb = q0 + w * 16 + lq * 4;
#pragma unroll
    for (int nb = 0; nb < 8; nb++)
#pragma unroll
        for (int r = 0; r < 4; r++)
            Oout[(((size_t)b * SS + rowb + r) * NQ + h) * HD + nb * 16 + lr] =
                toB(Oa[nb][r] * linv[r]);
}

// ---------------------------------------------------------------------------
extern "C" void kernel_launch(void* const* d_in, const int* in_sizes, int n_in,
                              void* d_out, int out_size, void* d_ws, size_t ws_size,
                              hipStream_t stream) {
    const float* x  = (const float*)d_in[0];
    const float* Wq = (const float*)d_in[1];
    const float* bq = (const float*)d_in[2];
    const float* Wk = (const float*)d_in[3];
    const float* bk = (const float*)d_in[4];
    const float* Wv = (const float*)d_in[5];
    const float* bv = (const float*)d_in[6];
    const float* Wo = (const float*)d_in[7];
    const float* bo = (const float*)d_in[8];
    float* out = (float*)d_out;

    const int M   = BB * SS;       // 4096
    const int DQ  = NQ * HD;       // 2048
    const int DKV = NKV * HD;      // 512
    const int NPK = DQ + 2 * DKV;  // 3072

    bf16* xb     = (bf16*)d_ws;                       // 4096*2048
    bf16* WqkvT  = xb + (size_t)M * EE;               // 3072*2048
    bf16* WoT    = WqkvT + (size_t)NPK * EE;          // 2048*2048
    bf16* Qb     = WoT + (size_t)EE * DQ;             // 4096*2048 (attn out in-place)
    bf16* Kb     = Qb + (size_t)M * DQ;               // 4096*512
    bf16* Vb     = Kb + (size_t)M * DKV;              // 4096*512  (V^T layout)

    convert_bf16<<<(M * EE / 4 + 255) / 256, 256, 0, stream>>>(x, xb, M * EE);
    convert_transpose_qkv<<<dim3(NPK / 32, EE / 32), 256, 0, stream>>>(Wq, Wk, Wv, WqkvT);
    convert_transpose<<<dim3(DQ / 32, DQ / 32), 256, 0, stream>>>(Wo, WoT, DQ, EE);

    // QKV projection + bias + RoPE; 128x128, ring-3, 3 blocks/CU, grid 768
    mfma_gemm_v7<1><<<dim3(NPK / 128, M / 128), 256, 0, stream>>>(
        xb, WqkvT, bq, bk, bv, nullptr, Qb, Kb, Vb, M, NPK, EE);

    attn_mfma<<<dim3(SS / 64, NQ, BB), 256, 0, stream>>>(Qb, Kb, Vb, Qb);

    // out projection; 128x128, ring-3, grid 512
    mfma_gemm_v7<0><<<dim3(EE / 128, M / 128), 256, 0, stream>>>(
        Qb, WoT, bo, nullptr, nullptr, out, nullptr, nullptr, nullptr, M, EE, DQ);
}